// Round 5
// baseline (356.133 us; speedup 1.0000x reference)
//
#include <hip/hip_runtime.h>
#include <stdint.h>
#include <stddef.h>

// ---------------------------------------------------------------------------
// CausalSelfAttention forward, MI355X/gfx950.
// Pipeline: cvt_all -> GEMM1(qkv) -> norm+rope+transpose -> attn_fwd3 ->
//           GEMM2(out proj, fp32)
// R5: GEMM BK=64 (half the barrier drains) with XOR-swizzled LDS layout
//     (128B rows would be 16-way conflicted; swizzle restores balanced
//     8/group = b128 baseline). GEMM2 uses MT=64 tile -> 768 blocks (3/CU).
//     attn: 8 waves/block, one 16-row frag per wave, grid (16,32)=512 blocks
//     (2/CU, 32 waves/CU) so barrier drains overlap across blocks.
// ---------------------------------------------------------------------------

typedef __attribute__((ext_vector_type(8))) __bf16 bf16x8;
typedef __attribute__((ext_vector_type(4))) __bf16 bf16x4;
typedef __attribute__((ext_vector_type(4))) float  f32x4;

#define NB 2
#define NT 2048
#define NC 1536
#define NH 16
#define ND 96
#define NQKV 4608          // 3*NC
#define NM 4096            // NB*NT

static __device__ __forceinline__ float fexp2(float x) {
#if __has_builtin(__builtin_amdgcn_exp2f)
  return __builtin_amdgcn_exp2f(x);
#else
  return exp2f(x);
#endif
}

// async global->LDS, 16B per lane; LDS dest = wave-uniform base + lane*16
static __device__ __forceinline__ void g2lds16(const void* g, void* l) {
  __builtin_amdgcn_global_load_lds(
      (const __attribute__((address_space(1))) void*)g,
      (__attribute__((address_space(3))) void*)l, 16, 0, 0);
}

// ---------------------------------------------------------------------------
// fused fp32 -> bf16 conversion for x, W_qkv, W_out (one launch)
// ---------------------------------------------------------------------------
__global__ __launch_bounds__(256) void cvt_all(
    const float4* __restrict__ x, const float4* __restrict__ wq,
    const float4* __restrict__ wo, bf16x4* __restrict__ xb,
    bf16x4* __restrict__ wqb, bf16x4* __restrict__ wob) {
  const int i  = blockIdx.x * 256 + threadIdx.x;
  const int n0 = NM * NC / 4;
  const int n1 = n0 + NQKV * NC / 4;
  const float4* s;
  bf16x4* d;
  int j;
  if (i < n0)      { s = x;  d = xb;  j = i; }
  else if (i < n1) { s = wq; d = wqb; j = i - n0; }
  else             { s = wo; d = wob; j = i - n1; }
  const float4 v = s[j];
  bf16x4 o;
  o[0] = (__bf16)v.x; o[1] = (__bf16)v.y;
  o[2] = (__bf16)v.z; o[3] = (__bf16)v.w;
  d[j] = o;
}

// ---------------------------------------------------------------------------
// GEMM: C[m][n] = sum_k A[m][k] * B[n][k]   (A: MxK bf16, B: NxK bf16)
// Tile MT x 128, BK=64, 4 waves (2x2), wave tile (MT/2) x 64, mfma 16x16x32.
// LDS rows are 128B (64 bf16): 16B chunks XOR-swizzled by (row&7) at stage
// time (source-address permutation; g2lds16 dest is fixed) so frag ds_reads
// hit balanced 8-lanes-per-bank-group instead of 16-way conflicts.
// ---------------------------------------------------------------------------
template <int MT>
__global__ __launch_bounds__(256) void gemm_bt(
    const __bf16* __restrict__ A, const __bf16* __restrict__ Bw,
    float* __restrict__ Cf, __bf16* __restrict__ Cb, int M, int N, int K) {
  constexpr int MI = MT / 32;           // acc row-frags per wave (4 or 2)
  __shared__ __align__(16) __bf16 Al[MT * 64];
  __shared__ __align__(16) __bf16 Bl[128 * 64];
  const int tid = threadIdx.x;
  const int l   = tid & 63;
  const int w   = tid >> 6;
  const int m0  = blockIdx.y * MT;
  const int n0  = blockIdx.x * 128;
  const int wm  = (w >> 1) * (MT / 2);
  const int wn  = (w & 1) * 64;
  const int lm  = l & 15;
  const int lq  = l >> 4;
  // staging: chunk = 8 rows x 128B; lane l covers row l>>3, source 16B-chunk
  // (l&7)^(l>>3)  -> LDS slot l&7 of row holds source chunk (l&7)^(row&7)
  const int srow = l >> 3;
  const int ssl  = ((l & 7) ^ srow) * 8;   // bf16 units

  f32x4 acc[MI][4] = {};

  for (int k0 = 0; k0 < K; k0 += 64) {
#pragma unroll
    for (int j = 0; j < MT / 32; ++j) {
      const int ci = w * (MT / 32) + j;
      g2lds16(A + (size_t)(m0 + ci * 8 + srow) * K + k0 + ssl,
              (char*)Al + ci * 1024);
    }
#pragma unroll
    for (int j = 0; j < 4; ++j) {
      const int ci = w * 4 + j;
      g2lds16(Bw + (size_t)(n0 + ci * 8 + srow) * K + k0 + ssl,
              (char*)Bl + ci * 1024);
    }
    __syncthreads();
#pragma unroll
    for (int kk = 0; kk < 2; ++kk) {
      const int sl = ((kk * 4 + lq) ^ (lm & 7)) * 8;  // un-swizzle
      bf16x8 af[MI], bfr[4];
#pragma unroll
      for (int mi = 0; mi < MI; ++mi)
        af[mi] = *(const bf16x8*)(Al + (wm + mi * 16 + lm) * 64 + sl);
#pragma unroll
      for (int ni = 0; ni < 4; ++ni)
        bfr[ni] = *(const bf16x8*)(Bl + (wn + ni * 16 + lm) * 64 + sl);
#pragma unroll
      for (int mi = 0; mi < MI; ++mi)
#pragma unroll
        for (int ni = 0; ni < 4; ++ni)
          acc[mi][ni] = __builtin_amdgcn_mfma_f32_16x16x32_bf16(
              af[mi], bfr[ni], acc[mi][ni], 0, 0, 0);
    }
    __syncthreads();
  }

  // epilogue: C/D layout col=lane&15, row=(lane>>4)*4+r  (m89/m91 verified)
  const int r0 = lq * 4;
#pragma unroll
  for (int mi = 0; mi < MI; ++mi)
#pragma unroll
    for (int ni = 0; ni < 4; ++ni)
#pragma unroll
      for (int r = 0; r < 4; ++r) {
        const size_t row = (size_t)(m0 + wm + mi * 16 + r0 + r);
        const size_t col = (size_t)(n0 + wn + ni * 16 + lm);
        if (Cf) Cf[row * N + col] = acc[mi][ni][r];
        else    Cb[row * N + col] = (__bf16)acc[mi][ni][r];
      }
}

// ---------------------------------------------------------------------------
// qk RMS-norm + 3D RoPE + layout transform.
// ---------------------------------------------------------------------------
static __device__ __forceinline__ float rope_one(float v, float p, int d,
                                                 const float* c3) {
  const int a  = d >> 5;        // which of 3 coord axes (d3=32)
  const int j  = d & 31;
  const int jj = j & 15;        // half=16
  const float invf = fexp2((float)jj * -0.8304820237218406f);
  const float ang  = c3[a] * invf;
  float sn, cs;
  __sincosf(ang, &sn, &cs);
  return (j < 16) ? (v * cs - p * sn) : (v * cs + p * sn);
}

__global__ __launch_bounds__(256) void normrope_kernel(
    const __bf16* __restrict__ qkv, const float* __restrict__ coords,
    const int* __restrict__ ttype, const float* __restrict__ qsc,
    const float* __restrict__ ksc, __bf16* __restrict__ qo,
    __bf16* __restrict__ ko, __bf16* __restrict__ vo) {
  const int l   = threadIdx.x & 63;
  const int w   = threadIdx.x >> 6;
  const int rid = blockIdx.x * 4 + w;       // (b*T+t)*H + h
  const int h   = rid & (NH - 1);
  const int bt  = rid >> 4;
  const int t   = bt & (NT - 1);
  const int b   = bt >> 11;                 // T = 2048
  const __bf16* base = qkv + (size_t)bt * NQKV + h * ND;
  const float*  c3   = coords + (size_t)bt * 3;
  const bool rope    = ttype[bt] > 0;
  const size_t bh    = (size_t)(b * NH + h);

  // ---- q ----
  {
    float x0 = (float)base[l];
    float x1 = (l < 32) ? (float)base[64 + l] : 0.f;
    float ss = x0 * x0 + x1 * x1;
#pragma unroll
    for (int off = 1; off < 64; off <<= 1) ss += __shfl_xor(ss, off, 64);
    const float rn = rsqrtf(ss * (1.f / 96.f) + 1e-6f);
    x0 *= rn * qsc[l];
    if (l < 32) x1 *= rn * qsc[64 + l];
    const float p0 = __shfl_xor(x0, 16, 64);
    const float p1 = __shfl_xor(x1, 16, 64);
    if (rope) {
      x0 = rope_one(x0, p0, l, c3);
      if (l < 32) x1 = rope_one(x1, p1, 64 + l, c3);
    }
    __bf16* dst = qo + (bh * NT + t) * ND;
    dst[l] = (__bf16)x0;
    if (l < 32) dst[64 + l] = (__bf16)x1;
  }
  // ---- k ----
  {
    float x0 = (float)base[NC + l];
    float x1 = (l < 32) ? (float)base[NC + 64 + l] : 0.f;
    float ss = x0 * x0 + x1 * x1;
#pragma unroll
    for (int off = 1; off < 64; off <<= 1) ss += __shfl_xor(ss, off, 64);
    const float rn = rsqrtf(ss * (1.f / 96.f) + 1e-6f);
    x0 *= rn * ksc[l];
    if (l < 32) x1 *= rn * ksc[64 + l];
    const float p0 = __shfl_xor(x0, 16, 64);
    const float p1 = __shfl_xor(x1, 16, 64);
    if (rope) {
      x0 = rope_one(x0, p0, l, c3);
      if (l < 32) x1 = rope_one(x1, p1, 64 + l, c3);
    }
    __bf16* dst = ko + (bh * NT + t) * ND;
    dst[l] = (__bf16)x0;
    if (l < 32) dst[64 + l] = (__bf16)x1;
  }
  // ---- v (transpose only) ----
  {
    vo[(bh * ND + l) * NT + t] = base[2 * NC + l];
    if (l < 32) vo[(bh * ND + 64 + l) * NT + t] = base[2 * NC + 64 + l];
  }
}

// ---------------------------------------------------------------------------
// Flash attention with LDS-staged K/V, fixed-max softmax.
// q,k: (B,H,T,D) bf16; vT: (B,H,D,T) bf16; out: (B,T,H,D)=(B*T,C) bf16.
// Grid (16, B*H), block = 8 waves (512 thr). Wave w owns ONE 16-row q-frag
// at qt*128 + w*16 (qt = 15-blockIdx.x: biggest blocks launch first).
// Per 32-key tile: stage K(6KB)+vT(6KB) -> LDS once per block (g2lds16,
// source-permuted into fragment-read order), double-buffered, stage for
// kt+1 issued right after the barrier. Waves past their causal bound idle
// at the barrier (wave-uniform guard). 512 blocks -> 2/CU, 32 waves/CU.
// ---------------------------------------------------------------------------
static __device__ __forceinline__ void attn_tile(
    const bf16x8 (&aq)[3], const bf16x8 (&bk)[2][3], int q0r, int n0,
    int lm, int lq, f32x4& lsum, __bf16* pbase /* 16 rows x 40 */) {
  f32x4 s[2];
#pragma unroll
  for (int nt = 0; nt < 2; ++nt) {
    f32x4 a = {};
#pragma unroll
    for (int c = 0; c < 3; ++c)
      a = __builtin_amdgcn_mfma_f32_16x16x32_bf16(aq[c], bk[nt][c], a, 0, 0, 0);
    s[nt] = a;
  }
  if (n0 + 31 > q0r) {   // diagonal-straddling tile: causal mask
#pragma unroll
    for (int nt = 0; nt < 2; ++nt)
#pragma unroll
      for (int r = 0; r < 4; ++r)
        if (n0 + nt * 16 + lm > q0r + lq * 4 + r) s[nt][r] = -1e30f;
  }
  const float cl = 0.10206207261596575f * 1.4426950408889634f;
#pragma unroll
  for (int nt = 0; nt < 2; ++nt)
#pragma unroll
    for (int r = 0; r < 4; ++r)
      s[nt][r] = fexp2((s[nt][r] - 96.0f) * cl);
#pragma unroll
  for (int r = 0; r < 4; ++r) lsum[r] += s[0][r] + s[1][r];
#pragma unroll
  for (int nt = 0; nt < 2; ++nt)
#pragma unroll
    for (int r = 0; r < 4; ++r)
      pbase[(lq * 4 + r) * 40 + nt * 16 + lm] = (__bf16)s[nt][r];
}

__global__ __launch_bounds__(512) void attn_fwd3(
    const __bf16* __restrict__ q, const __bf16* __restrict__ k,
    const __bf16* __restrict__ vt, __bf16* __restrict__ out) {
  __shared__ __align__(16) char KV[2][12288];        // [buf][K 6KB | V 6KB]
  __shared__ __align__(16) __bf16 plds[8][16][40];
  const int tid = threadIdx.x;
  const int l   = tid & 63;
  const int w   = tid >> 6;          // 0..7
  const int bh  = blockIdx.y;
  const int qt  = 15 - blockIdx.x;   // biggest (most keys) first
  const int lm  = l & 15;
  const int lq  = l >> 4;
  const int q0   = qt * 128 + w * 16;
  const int nktw = qt * 4 + (w >> 1) + 1;   // this wave's causal bound
  const int nkt  = qt * 4 + 4;              // block loop bound (<= 64)
  const __bf16* qh = q  + (size_t)bh * NT * ND;
  const __bf16* kh = k  + (size_t)bh * NT * ND;
  const __bf16* vh = vt + (size_t)bh * ND * NT;
  __bf16* pb = &plds[w][0][0];

  // stage tile at key n0. K chunk (nt*3+c): 64 lanes' 16B = fragment-read
  // order; V chunk dt likewise.
  auto stage = [&](int n0, char* buf) {
    if (w < 6) {
      const int nt = w / 3, c = w - nt * 3;
      g2lds16(kh + (size_t)(n0 + nt * 16 + (l >> 2)) * ND + c * 32 + (l & 3) * 8,
              buf + w * 1024);
    } else {
      const int v = w - 6;
      g2lds16(vh + (size_t)(v * 16 + (l >> 2)) * NT + n0 + (l & 3) * 8,
              buf + 6144 + v * 1024);
    }
    if (w < 4) {
      const int v = 2 + w;
      g2lds16(vh + (size_t)(v * 16 + (l >> 2)) * NT + n0 + (l & 3) * 8,
              buf + 6144 + v * 1024);
    }
  };

  bf16x8 aq[3];
#pragma unroll
  for (int c = 0; c < 3; ++c)
    aq[c] = *(const bf16x8*)(qh + (size_t)(q0 + lm) * ND + c * 32 + lq * 8);

  f32x4 o[6] = {};
  f32x4 ls = {};
  const int ji = (lm * 4 + lq) * 16;   // this lane's chunk byte offset

  stage(0, KV[0]);
  for (int kt = 0; kt < nkt; ++kt) {
    __syncthreads();                   // drains stage(kt); all waves done kt-1
    if (kt + 1 < nkt) stage((kt + 1) * 32, KV[(kt + 1) & 1]);
    if (kt < nktw) {                   // wave-uniform causal guard
      const char* Kc = KV[kt & 1];
      const char* Vc = KV[kt & 1] + 6144;
      const int n0 = kt * 32;
      bf16x8 bk[2][3];
#pragma unroll
      for (int nt = 0; nt < 2; ++nt)
#pragma unroll
        for (int c = 0; c < 3; ++c)
          bk[nt][c] = *(const bf16x8*)(Kc + (nt * 3 + c) * 1024 + ji);
      attn_tile(aq, bk, q0, n0, lm, lq, ls, pb);
      bf16x8 ap = *(const bf16x8*)(pb + lm * 40 + lq * 8);
#pragma unroll
      for (int dt = 0; dt < 6; ++dt) {
        bf16x8 bv = *(const bf16x8*)(Vc + dt * 1024 + ji);
        o[dt] = __builtin_amdgcn_mfma_f32_16x16x32_bf16(ap, bv, o[dt], 0, 0, 0);
      }
    }
  }

  // epilogue: out[(b*T+t), h*96+d]
  const int b = bh >> 4, h = bh & 15;
  float rl[4];
#pragma unroll
  for (int r = 0; r < 4; ++r) {
    float v = ls[r];
#pragma unroll
    for (int off = 1; off < 16; off <<= 1) v += __shfl_xor(v, off, 64);
    rl[r] = 1.f / v;
  }
#pragma unroll
  for (int dt = 0; dt < 6; ++dt)
#pragma unroll
    for (int r = 0; r < 4; ++r) {
      const int t = q0 + lq * 4 + r;
      out[((size_t)(b * NT + t)) * NC + h * ND + dt * 16 + lm] =
          (__bf16)(o[dt][r] * rl[r]);
    }
}

// ---------------------------------------------------------------------------
// workspace layout (bytes); attn-out aliases xb (dead after GEMM1)
// ---------------------------------------------------------------------------
static constexpr size_t OFF_XB   = 0;          // 12,582,912  (also attn out)
static constexpr size_t OFF_WQKV = 12582912;   // 14,155,776
static constexpr size_t OFF_WOUT = 26738688;   //  4,718,592
static constexpr size_t OFF_QKV  = 31457280;   // 37,748,736
static constexpr size_t OFF_Q    = 69206016;   // 12,582,912
static constexpr size_t OFF_K    = 81788928;   // 12,582,912
static constexpr size_t OFF_VT   = 94371840;   // 12,582,912  -> end 106,954,752

extern "C" void kernel_launch(void* const* d_in, const int* in_sizes, int n_in,
                              void* d_out, int out_size, void* d_ws,
                              size_t ws_size, hipStream_t stream) {
  const float* x      = (const float*)d_in[0];
  const float* coords = (const float*)d_in[1];
  const int*   ttype  = (const int*)d_in[2];
  const float* wqkv   = (const float*)d_in[3];
  const float* wout   = (const float*)d_in[4];
  const float* qs     = (const float*)d_in[5];
  const float* ks     = (const float*)d_in[6];

  char* ws = (char*)d_ws;
  __bf16* xb    = (__bf16*)(ws + OFF_XB);
  __bf16* wqkvb = (__bf16*)(ws + OFF_WQKV);
  __bf16* woutb = (__bf16*)(ws + OFF_WOUT);
  __bf16* qkvb  = (__bf16*)(ws + OFF_QKV);
  __bf16* qb    = (__bf16*)(ws + OFF_Q);
  __bf16* kb    = (__bf16*)(ws + OFF_K);
  __bf16* vtb   = (__bf16*)(ws + OFF_VT);
  __bf16* attnb = (__bf16*)(ws + OFF_XB);   // alias

  // 1. fp32 -> bf16 conversions (single fused launch; 15360*256 = exact)
  cvt_all<<<15360, 256, 0, stream>>>(
      (const float4*)x, (const float4*)wqkv, (const float4*)wout,
      (bf16x4*)xb, (bf16x4*)wqkvb, (bf16x4*)woutb);
  // 2. qkv = x @ W_qkv^T  (bf16 out)
  gemm_bt<128><<<dim3(NQKV / 128, NM / 128), 256, 0, stream>>>(
      xb, wqkvb, nullptr, qkvb, NM, NQKV, NC);
  // 3. qk-norm + rope + v-transpose
  normrope_kernel<<<(NB * NT * NH) / 4, 256, 0, stream>>>(
      qkvb, coords, ttype, qs, ks, qb, kb, vtb);
  // 4. causal attention (LDS-staged K/V, 8 frag-waves per block)
  attn_fwd3<<<dim3(16, NB * NH), 512, 0, stream>>>(qb, kb, vtb, attnb);
  // 5. out = attn @ W_out^T (fp32 out), MT=64 tile -> 768 blocks
  gemm_bt<64><<<dim3(NC / 128, NM / 64), 256, 0, stream>>>(
      attnb, woutb, (float*)d_out, nullptr, NM, NC, NC);
}